// Round 3
// baseline (291.479 us; speedup 1.0000x reference)
//
#include <hip/hip_runtime.h>
#include <hip/hip_bf16.h>
#include <math.h>

#define DTC 0.01f

typedef __attribute__((ext_vector_type(8))) short short8;   // 8 x bf16 (4 VGPRs)
typedef __attribute__((ext_vector_type(4))) float f32x4;    // MFMA C/D
typedef unsigned short bf16raw;

__device__ __forceinline__ bf16raw f2bf(float f){
  union { unsigned u; float f; } v; v.f = f;
  unsigned r = v.u + 0x7FFF + ((v.u >> 16) & 1u);   // round-to-nearest-even
  return (bf16raw)(r >> 16);
}

// Load 8 consecutive fp32, round to 8 bf16 (one short8, 16B).
__device__ __forceinline__ short8 ld8f(const float* __restrict__ p){
  float4 a = *(const float4*)p;
  float4 b = *(const float4*)(p + 4);
  short8 r;
  r[0] = (short)f2bf(a.x); r[1] = (short)f2bf(a.y);
  r[2] = (short)f2bf(a.z); r[3] = (short)f2bf(a.w);
  r[4] = (short)f2bf(b.x); r[5] = (short)f2bf(b.y);
  r[6] = (short)f2bf(b.z); r[7] = (short)f2bf(b.w);
  return r;
}

// One BK=32 step: 4 A-frags + 4 B-frags (ds_read_b128) + 16 MFMA.
// A-operand: lane holds A[m = lane&15][k = quad*8 + j]; C/D: col=lane&15,
// row=quad*4+reg (verified mapping).
__device__ __forceinline__ void mma_step(const bf16raw* Alds, const bf16raw* Blds,
                                         f32x4 acc[4][4], int wm, int wn, int quad, int t16){
  short8 af[4], bfr[4];
#pragma unroll
  for (int mi = 0; mi < 4; ++mi)
    af[mi] = *(const short8*)(Alds + (wm*64 + mi*16 + t16)*32 + quad*8);
#pragma unroll
  for (int ni = 0; ni < 4; ++ni)
    bfr[ni] = *(const short8*)(Blds + (wn*64 + ni*16 + t16)*32 + quad*8);
#pragma unroll
  for (int mi = 0; mi < 4; ++mi)
#pragma unroll
    for (int ni = 0; ni < 4; ++ni)
      acc[mi][ni] = __builtin_amdgcn_mfma_f32_16x16x32_bf16(af[mi], bfr[ni], acc[mi][ni], 0, 0, 0);
}

// ---------------------------------------------------------------------------
// K1: P[bt][n] = sum_d u[bt][d] * W[n][d]   (16384 x 256, K=1024), fp32 out.
// W rows selected per-n from {W_omega, W_zeta, W_B}. fp32 inputs, bf16 MFMA.
// ---------------------------------------------------------------------------
extern "C" __global__ __launch_bounds__(256) void k_gemm_p(
    const float* __restrict__ u,
    const float* __restrict__ Wom, const float* __restrict__ Wze,
    const float* __restrict__ WB, float* __restrict__ P){
  __shared__ __align__(16) bf16raw Alds[128*32];
  __shared__ __align__(16) bf16raw Blds[128*32];
  int tid = threadIdx.x, wave = tid >> 6, lane = tid & 63;
  int quad = lane >> 4, t16 = lane & 15;
  int wm = wave >> 1, wn = wave & 1;
  long row0 = (long)blockIdx.y * 128;
  int  col0 = blockIdx.x * 128;

  int srow = tid >> 2;            // 0..63: two rows per thread (srow, srow+64)
  int sk = (tid & 3) * 8;         // 4 threads x 8 elems = 32 k-elems per row
  int  n  = col0 + srow;
  const float* wrow0 = (n < 64) ? (Wom + (size_t)n*1024)
                     : (n < 128) ? (Wze + (size_t)(n-64)*1024)
                                 : (WB  + (size_t)(n-128)*1024);
  int  n2 = col0 + srow + 64;
  const float* wrow1 = (n2 < 128) ? (Wze + (size_t)(n2-64)*1024)
                                  : (WB  + (size_t)(n2-128)*1024);
  f32x4 acc[4][4] = {};
  for (int kt = 0; kt < 32; ++kt){
    int k0 = kt*32;
    short8 a0 = ld8f(u + (row0 + srow     )*1024 + k0 + sk);
    short8 a1 = ld8f(u + (row0 + srow + 64)*1024 + k0 + sk);
    short8 b0 = ld8f(wrow0 + k0 + sk);
    short8 b1 = ld8f(wrow1 + k0 + sk);
    __syncthreads();
    *(short8*)(Alds + (srow     )*32 + sk) = a0;
    *(short8*)(Alds + (srow + 64)*32 + sk) = a1;
    *(short8*)(Blds + (srow     )*32 + sk) = b0;
    *(short8*)(Blds + (srow + 64)*32 + sk) = b1;
    __syncthreads();
    mma_step(Alds, Blds, acc, wm, wn, quad, t16);
  }
#pragma unroll
  for (int mi = 0; mi < 4; ++mi)
#pragma unroll
    for (int ni = 0; ni < 4; ++ni)
#pragma unroll
      for (int r = 0; r < 4; ++r){
        long grow = row0 + wm*64 + mi*16 + quad*4 + r;
        int  gcol = col0 + wn*64 + ni*16 + t16;
        P[grow*256 + gcol] = acc[mi][ni][r];
      }
}

// ---------------------------------------------------------------------------
// K4: out[bt][d] = sum_n xs[bt][n]*C[d][n] + sum_e u[bt][e]*Dm[d][e], fp32 out.
// Split-K: phase 1 Xs@C^T (K=128, Xs already bf16), phase 2 u@Dm^T (K=1024).
// ---------------------------------------------------------------------------
extern "C" __global__ __launch_bounds__(256) void k_gemm_out(
    const bf16raw* __restrict__ Xs, const float* __restrict__ u,
    const float* __restrict__ Cmat, const float* __restrict__ Dm,
    float* __restrict__ out){
  __shared__ __align__(16) bf16raw Alds[128*32];
  __shared__ __align__(16) bf16raw Blds[128*32];
  int tid = threadIdx.x, wave = tid >> 6, lane = tid & 63;
  int quad = lane >> 4, t16 = lane & 15;
  int wm = wave >> 1, wn = wave & 1;
  long row0 = (long)blockIdx.y * 128;
  int  col0 = blockIdx.x * 128;
  int srow = tid >> 2;
  int sk = (tid & 3) * 8;
  f32x4 acc[4][4] = {};
  for (int kt = 0; kt < 4; ++kt){            // phase 1: xs @ C^T
    int k0 = kt*32;
    short8 a0 = *(const short8*)(Xs + (row0 + srow     )*128 + k0 + sk);
    short8 a1 = *(const short8*)(Xs + (row0 + srow + 64)*128 + k0 + sk);
    short8 b0 = ld8f(Cmat + (size_t)(col0 + srow     )*128 + k0 + sk);
    short8 b1 = ld8f(Cmat + (size_t)(col0 + srow + 64)*128 + k0 + sk);
    __syncthreads();
    *(short8*)(Alds + (srow     )*32 + sk) = a0;
    *(short8*)(Alds + (srow + 64)*32 + sk) = a1;
    *(short8*)(Blds + (srow     )*32 + sk) = b0;
    *(short8*)(Blds + (srow + 64)*32 + sk) = b1;
    __syncthreads();
    mma_step(Alds, Blds, acc, wm, wn, quad, t16);
  }
  for (int kt = 0; kt < 32; ++kt){           // phase 2: u @ Dm^T
    int k0 = kt*32;
    short8 a0 = ld8f(u + (row0 + srow     )*1024 + k0 + sk);
    short8 a1 = ld8f(u + (row0 + srow + 64)*1024 + k0 + sk);
    short8 b0 = ld8f(Dm + (size_t)(col0 + srow     )*1024 + k0 + sk);
    short8 b1 = ld8f(Dm + (size_t)(col0 + srow + 64)*1024 + k0 + sk);
    __syncthreads();
    *(short8*)(Alds + (srow     )*32 + sk) = a0;
    *(short8*)(Alds + (srow + 64)*32 + sk) = a1;
    *(short8*)(Blds + (srow     )*32 + sk) = b0;
    *(short8*)(Blds + (srow + 64)*32 + sk) = b1;
    __syncthreads();
    mma_step(Alds, Blds, acc, wm, wn, quad, t16);
  }
#pragma unroll
  for (int mi = 0; mi < 4; ++mi)
#pragma unroll
    for (int ni = 0; ni < 4; ++ni)
#pragma unroll
      for (int r = 0; r < 4; ++r){
        long grow = row0 + wm*64 + mi*16 + quad*4 + r;
        int  gcol = col0 + wn*64 + ni*16 + t16;
        out[grow*1024 + gcol] = acc[mi][ni][r];
      }
}

// ---------------------------------------------------------------------------
// Coefficients: per (bt, m): p = d*S, q = DT*A*p, carry Fz/Fy.
// ---------------------------------------------------------------------------
extern "C" __global__ void k_coef(const float* __restrict__ P,
    const float* __restrict__ b_om, const float* __restrict__ b_ze,
    const float* __restrict__ b_B, float4* __restrict__ Coef){
  int idx = blockIdx.x * 256 + threadIdx.x;   // 16384*64 threads
  int bt = idx >> 6, m = idx & 63;
  const float* row = P + (size_t)bt * 256;
  float wo = row[m]       + b_om[m];
  float wz = row[64 + m]  + b_ze[m];
  float fz = row[128 + m] + b_B[m];
  float fy = row[192 + m] + b_B[64 + m];
  float sp = (wo > 20.f) ? wo : log1pf(expf(wo));
  float omega = fminf(fmaxf(sp, 1e-4f), 100.f);
  float A = omega * omega;
  float S = 1.f / (1.f + DTC*DTC*A);
  float zeta = 1.f / (1.f + expf(-wz));
  float d = 1.f - zeta;
  float p = d * S;
  float q = p * DTC * A;
  Coef[idx] = make_float4(p, q, fz, fy);
}

// ---------------------------------------------------------------------------
// Chunked exact scan: 128 chunks x 32 steps; tid = b*64 + m (256 series).
// ---------------------------------------------------------------------------
extern "C" __global__ void k_scan1(const float4* __restrict__ Coef,
    float4* __restrict__ CM, float2* __restrict__ CV){
  int tid = threadIdx.x, c = blockIdx.x;
  int b = tid >> 6, m = tid & 63;
  const float4* cf = Coef + ((size_t)b*4096 + c*32)*64 + m;
  float m00=1.f, m01=0.f, m10=0.f, m11=0.f, vz=0.f, vy=0.f;
#pragma unroll 4
  for (int t = 0; t < 32; ++t){
    float4 f = cf[t*64];
    float p = f.x, q = f.y;
    float nvz = p*vz - q*vy + f.z;
    float nvy = DTC*p*vz + p*vy + f.w;
    vz = nvz; vy = nvy;
    float n00 = p*m00 - q*m10;
    float n01 = p*m01 - q*m11;
    float n10 = DTC*p*m00 + p*m10;
    float n11 = DTC*p*m01 + p*m11;
    m00=n00; m01=n01; m10=n10; m11=n11;
  }
  CM[c*256 + tid] = make_float4(m00, m01, m10, m11);
  CV[c*256 + tid] = make_float2(vz, vy);
}

extern "C" __global__ void k_scan2(const float4* __restrict__ CM,
    const float2* __restrict__ CV, float2* __restrict__ XIn){
  int tid = threadIdx.x;
  float xz = 0.f, xy = 0.f;
  for (int c = 0; c < 128; ++c){
    XIn[c*256 + tid] = make_float2(xz, xy);
    float4 Mv = CM[c*256 + tid];
    float2 Vv = CV[c*256 + tid];
    float nz = Mv.x*xz + Mv.y*xy + Vv.x;
    float ny = Mv.z*xz + Mv.w*xy + Vv.y;
    xz = nz; xy = ny;
  }
}

extern "C" __global__ void k_scan3(const float4* __restrict__ Coef,
    const float2* __restrict__ XIn, bf16raw* __restrict__ Xs){
  int tid = threadIdx.x, c = blockIdx.x;
  int b = tid >> 6, m = tid & 63;
  const float4* cf = Coef + ((size_t)b*4096 + c*32)*64 + m;
  float2 x0 = XIn[c*256 + tid];
  float xz = x0.x, xy = x0.y;
  bf16raw* xp = Xs + ((size_t)b*4096 + c*32)*128 + m;
#pragma unroll 4
  for (int t = 0; t < 32; ++t){
    float4 f = cf[t*64];
    float p = f.x, q = f.y;
    float nz = p*xz - q*xy + f.z;
    float ny = DTC*p*xz + p*xy + f.w;
    xz = nz; xy = ny;
    xp[t*128]      = f2bf(xz);   // z part: n = m
    xp[t*128 + 64] = f2bf(xy);   // y part: n = 64 + m
  }
}

// ---------------------------------------------------------------------------
extern "C" void kernel_launch(void* const* d_in, const int* in_sizes, int n_in,
                              void* d_out, int out_size, void* d_ws, size_t ws_size,
                              hipStream_t stream){
  const float* u   = (const float*)d_in[0];
  const float* Wom = (const float*)d_in[1];
  const float* bom = (const float*)d_in[2];
  const float* Wze = (const float*)d_in[3];
  const float* bze = (const float*)d_in[4];
  const float* WB  = (const float*)d_in[5];
  const float* bB  = (const float*)d_in[6];
  const float* Cm  = (const float*)d_in[7];
  const float* Dm  = (const float*)d_in[8];
  float* out = (float*)d_out;

  char* ws = (char*)d_ws;
  size_t off = 0;
  float*   P    = (float*)  (ws + off); off += (size_t)16384*256*4;     // 16 MB
  float4*  Coef = (float4*) (ws + off); off += (size_t)16384*64*16;     // 16 MB
  float4*  CMw  = (float4*) (ws + off); off += (size_t)128*256*16;      // 512 KB
  float2*  CVw  = (float2*) (ws + off); off += (size_t)128*256*8;       // 256 KB
  float2*  XIn  = (float2*) (ws + off); off += (size_t)128*256*8;       // 256 KB
  bf16raw* Xs   = (bf16raw*)(ws + off); off += (size_t)16384*128*2;     // 4 MB

  k_gemm_p  <<<dim3(2, 128), 256, 0, stream>>>(u, Wom, Wze, WB, P);
  k_coef    <<<4096, 256, 0, stream>>>(P, bom, bze, bB, Coef);
  k_scan1   <<<128, 256, 0, stream>>>(Coef, CMw, CVw);
  k_scan2   <<<1, 256, 0, stream>>>(CMw, CVw, XIn);
  k_scan3   <<<128, 256, 0, stream>>>(Coef, XIn, Xs);
  k_gemm_out<<<dim3(8, 128), 256, 0, stream>>>(Xs, u, Cm, Dm, out);
}

// Round 4
// 232.993 us; speedup vs baseline: 1.2510x; 1.2510x over previous
//
#include <hip/hip_runtime.h>
#include <hip/hip_bf16.h>
#include <math.h>

#define DTC 0.01f

typedef __attribute__((ext_vector_type(8))) short short8;   // 8 x bf16 (4 VGPRs)
typedef __attribute__((ext_vector_type(4))) float f32x4;    // MFMA C/D
typedef unsigned short bf16raw;

__device__ __forceinline__ bf16raw f2bf(float f){
  union { unsigned u; float f; } v; v.f = f;
  unsigned r = v.u + 0x7FFF + ((v.u >> 16) & 1u);   // round-to-nearest-even
  return (bf16raw)(r >> 16);
}

// Load 8 consecutive fp32, round to 8 bf16.
__device__ __forceinline__ short8 ld8f(const float* __restrict__ p){
  float4 a = *(const float4*)p;
  float4 b = *(const float4*)(p + 4);
  short8 r;
  r[0] = (short)f2bf(a.x); r[1] = (short)f2bf(a.y);
  r[2] = (short)f2bf(a.z); r[3] = (short)f2bf(a.w);
  r[4] = (short)f2bf(b.x); r[5] = (short)f2bf(b.y);
  r[6] = (short)f2bf(b.z); r[7] = (short)f2bf(b.w);
  return r;
}

// ---------------------------------------------------------------------------
// Async-stage ITERS*16 rows x 32 bf16 (k-contiguous) -> LDS [row][32].
// Per instr: 64 lanes x 16B = 16 rows. LDS dest = wave-uniform base +
// lane*16B (HW scatter) — lane i covers row r0 + i/4, k-chunk (i%4)*8.
// ---------------------------------------------------------------------------
template<int ITERS>
__device__ __forceinline__ void stage_async(const bf16raw* __restrict__ src, long ld,
                                            long row0, int k0, bf16raw* lds,
                                            int wave, int lane){
#pragma unroll
  for (int i = 0; i < ITERS; ++i){
    int r0 = (wave*ITERS + i) * 16;
    long row = row0 + r0 + (lane >> 2);
    const bf16raw* gp = src + row*ld + k0 + (lane & 3)*8;
    bf16raw* lp = lds + r0*32;
    __builtin_amdgcn_global_load_lds((const __attribute__((address_space(1))) void*)gp,
                                     (__attribute__((address_space(3))) void*)lp,
                                     16, 0, 0);
  }
}

// One BK=32 step: 4 A-frags + NI B-frags (ds_read_b128) + 4*NI MFMA.
// A-operand: lane holds A[m=lane&15][k=quad*8+j]; C/D: col=lane&15, row=quad*4+reg.
template<int NI>
__device__ __forceinline__ void mma_tile(const bf16raw* Alds, const bf16raw* Blds,
                                         f32x4 acc[4][NI], int wm, int wn, int quad, int t16){
  short8 af[4], bfr[NI];
#pragma unroll
  for (int mi = 0; mi < 4; ++mi)
    af[mi] = *(const short8*)(Alds + (wm*64 + mi*16 + t16)*32 + quad*8);
#pragma unroll
  for (int ni = 0; ni < NI; ++ni)
    bfr[ni] = *(const short8*)(Blds + (wn*(NI*16) + ni*16 + t16)*32 + quad*8);
#pragma unroll
  for (int mi = 0; mi < 4; ++mi)
#pragma unroll
    for (int ni = 0; ni < NI; ++ni)
      acc[mi][ni] = __builtin_amdgcn_mfma_f32_16x16x32_bf16(af[mi], bfr[ni], acc[mi][ni], 0, 0, 0);
}

// ---------------------------------------------------------------------------
// Prep: fp32 -> bf16 for u, [W_omega|W_zeta|W_B] (concat), C, D_mat.
// One 8-elem group per thread; 2277376 groups = 8896 blocks x 256.
// ---------------------------------------------------------------------------
extern "C" __global__ void k_prep(const float* __restrict__ u,
    const float* __restrict__ Wom, const float* __restrict__ Wze,
    const float* __restrict__ WB, const float* __restrict__ Cm,
    const float* __restrict__ Dm, bf16raw* __restrict__ u_bf,
    bf16raw* __restrict__ Wcat, bf16raw* __restrict__ C_bf,
    bf16raw* __restrict__ Dm_bf){
  long g = (long)blockIdx.x * 256 + threadIdx.x;
  const float* src; bf16raw* dst; long o;
  if      (g < 2097152){ src = u;   dst = u_bf;          o = g; }
  else if (g < 2105344){ src = Wom; dst = Wcat;          o = g - 2097152; }
  else if (g < 2113536){ src = Wze; dst = Wcat + 65536;  o = g - 2105344; }
  else if (g < 2129920){ src = WB;  dst = Wcat + 131072; o = g - 2113536; }
  else if (g < 2146304){ src = Cm;  dst = C_bf;          o = g - 2129920; }
  else                 { src = Dm;  dst = Dm_bf;         o = g - 2146304; }
  *(short8*)(dst + o*8) = ld8f(src + o*8);
}

// ---------------------------------------------------------------------------
// K1: P[bt][n] = sum_d u[bt][d] * Wcat[n][d]  (16384 x 256, K=1024), fp32 out.
// ---------------------------------------------------------------------------
extern "C" __global__ __launch_bounds__(256) void k_gemm_p(
    const bf16raw* __restrict__ u_bf, const bf16raw* __restrict__ Wcat,
    float* __restrict__ P){
  __shared__ __align__(16) bf16raw Alds[128*32];
  __shared__ __align__(16) bf16raw Blds[128*32];
  int tid = threadIdx.x, wave = tid >> 6, lane = tid & 63;
  int quad = lane >> 4, t16 = lane & 15;
  int wm = wave >> 1, wn = wave & 1;
  long row0 = (long)blockIdx.y * 128;
  int  col0 = blockIdx.x * 128;
  f32x4 acc[4][4] = {};
  for (int kt = 0; kt < 32; ++kt){
    __syncthreads();
    stage_async<2>(u_bf, 1024, row0, kt*32, Alds, wave, lane);
    stage_async<2>(Wcat, 1024, col0, kt*32, Blds, wave, lane);
    __syncthreads();
    mma_tile<4>(Alds, Blds, acc, wm, wn, quad, t16);
  }
#pragma unroll
  for (int mi = 0; mi < 4; ++mi)
#pragma unroll
    for (int ni = 0; ni < 4; ++ni)
#pragma unroll
      for (int r = 0; r < 4; ++r){
        long grow = row0 + wm*64 + mi*16 + quad*4 + r;
        int  gcol = col0 + wn*64 + ni*16 + t16;
        P[grow*256 + gcol] = acc[mi][ni][r];
      }
}

// ---------------------------------------------------------------------------
// K4: out[bt][d] = sum_n Xs[bt][n]*C[d][n] + sum_e u[bt][e]*Dm[d][e], fp32 out.
// Tile 128x256 (acc 4x8) to halve A-operand re-reads. Split-K phases.
// ---------------------------------------------------------------------------
extern "C" __global__ __launch_bounds__(256, 2) void k_gemm_out(
    const bf16raw* __restrict__ Xs, const bf16raw* __restrict__ u_bf,
    const bf16raw* __restrict__ C_bf, const bf16raw* __restrict__ Dm_bf,
    float* __restrict__ out){
  __shared__ __align__(16) bf16raw Alds[128*32];
  __shared__ __align__(16) bf16raw Blds[256*32];
  int tid = threadIdx.x, wave = tid >> 6, lane = tid & 63;
  int quad = lane >> 4, t16 = lane & 15;
  int wm = wave >> 1, wn = wave & 1;
  long row0 = (long)blockIdx.y * 128;
  int  col0 = blockIdx.x * 256;
  f32x4 acc[4][8] = {};
  for (int kt = 0; kt < 4; ++kt){            // phase 1: Xs @ C^T (K=128)
    __syncthreads();
    stage_async<2>(Xs,   128, row0, kt*32, Alds, wave, lane);
    stage_async<4>(C_bf, 128, col0, kt*32, Blds, wave, lane);
    __syncthreads();
    mma_tile<8>(Alds, Blds, acc, wm, wn, quad, t16);
  }
  for (int kt = 0; kt < 32; ++kt){           // phase 2: u @ Dm^T (K=1024)
    __syncthreads();
    stage_async<2>(u_bf,  1024, row0, kt*32, Alds, wave, lane);
    stage_async<4>(Dm_bf, 1024, col0, kt*32, Blds, wave, lane);
    __syncthreads();
    mma_tile<8>(Alds, Blds, acc, wm, wn, quad, t16);
  }
#pragma unroll
  for (int mi = 0; mi < 4; ++mi)
#pragma unroll
    for (int ni = 0; ni < 8; ++ni)
#pragma unroll
      for (int r = 0; r < 4; ++r){
        long grow = row0 + wm*64 + mi*16 + quad*4 + r;
        int  gcol = col0 + wn*128 + ni*16 + t16;
        out[grow*1024 + gcol] = acc[mi][ni][r];
      }
}

// ---------------------------------------------------------------------------
// Coefficients: per (bt, m): p = d*S, q = DT*A*p, carry Fz/Fy.
// ---------------------------------------------------------------------------
extern "C" __global__ void k_coef(const float* __restrict__ P,
    const float* __restrict__ b_om, const float* __restrict__ b_ze,
    const float* __restrict__ b_B, float4* __restrict__ Coef){
  int idx = blockIdx.x * 256 + threadIdx.x;   // 16384*64 threads
  int bt = idx >> 6, m = idx & 63;
  const float* row = P + (size_t)bt * 256;
  float wo = row[m]       + b_om[m];
  float wz = row[64 + m]  + b_ze[m];
  float fz = row[128 + m] + b_B[m];
  float fy = row[192 + m] + b_B[64 + m];
  float sp = (wo > 20.f) ? wo : log1pf(expf(wo));
  float omega = fminf(fmaxf(sp, 1e-4f), 100.f);
  float A = omega * omega;
  float S = 1.f / (1.f + DTC*DTC*A);
  float zeta = 1.f / (1.f + expf(-wz));
  float d = 1.f - zeta;
  float p = d * S;
  float q = p * DTC * A;
  Coef[idx] = make_float4(p, q, fz, fy);
}

// ---------------------------------------------------------------------------
// Chunked exact scan: 128 chunks x 32 steps; tid = b*64 + m (256 series).
// ---------------------------------------------------------------------------
extern "C" __global__ void k_scan1(const float4* __restrict__ Coef,
    float4* __restrict__ CM, float2* __restrict__ CV){
  int tid = threadIdx.x, c = blockIdx.x;
  int b = tid >> 6, m = tid & 63;
  const float4* cf = Coef + ((size_t)b*4096 + c*32)*64 + m;
  float m00=1.f, m01=0.f, m10=0.f, m11=0.f, vz=0.f, vy=0.f;
#pragma unroll 4
  for (int t = 0; t < 32; ++t){
    float4 f = cf[t*64];
    float p = f.x, q = f.y;
    float nvz = p*vz - q*vy + f.z;
    float nvy = DTC*p*vz + p*vy + f.w;
    vz = nvz; vy = nvy;
    float n00 = p*m00 - q*m10;
    float n01 = p*m01 - q*m11;
    float n10 = DTC*p*m00 + p*m10;
    float n11 = DTC*p*m01 + p*m11;
    m00=n00; m01=n01; m10=n10; m11=n11;
  }
  CM[c*256 + tid] = make_float4(m00, m01, m10, m11);
  CV[c*256 + tid] = make_float2(vz, vy);
}

extern "C" __global__ void k_scan2(const float4* __restrict__ CM,
    const float2* __restrict__ CV, float2* __restrict__ XIn){
  int tid = threadIdx.x;
  float xz = 0.f, xy = 0.f;
#pragma unroll 4
  for (int c = 0; c < 128; ++c){
    XIn[c*256 + tid] = make_float2(xz, xy);
    float4 Mv = CM[c*256 + tid];
    float2 Vv = CV[c*256 + tid];
    float nz = Mv.x*xz + Mv.y*xy + Vv.x;
    float ny = Mv.z*xz + Mv.w*xy + Vv.y;
    xz = nz; xy = ny;
  }
}

extern "C" __global__ void k_scan3(const float4* __restrict__ Coef,
    const float2* __restrict__ XIn, bf16raw* __restrict__ Xs){
  int tid = threadIdx.x, c = blockIdx.x;
  int b = tid >> 6, m = tid & 63;
  const float4* cf = Coef + ((size_t)b*4096 + c*32)*64 + m;
  float2 x0 = XIn[c*256 + tid];
  float xz = x0.x, xy = x0.y;
  bf16raw* xp = Xs + ((size_t)b*4096 + c*32)*128 + m;
#pragma unroll 4
  for (int t = 0; t < 32; ++t){
    float4 f = cf[t*64];
    float p = f.x, q = f.y;
    float nz = p*xz - q*xy + f.z;
    float ny = DTC*p*xz + p*xy + f.w;
    xz = nz; xy = ny;
    xp[t*128]      = f2bf(xz);   // z part: n = m
    xp[t*128 + 64] = f2bf(xy);   // y part: n = 64 + m
  }
}

// ---------------------------------------------------------------------------
extern "C" void kernel_launch(void* const* d_in, const int* in_sizes, int n_in,
                              void* d_out, int out_size, void* d_ws, size_t ws_size,
                              hipStream_t stream){
  const float* u   = (const float*)d_in[0];
  const float* Wom = (const float*)d_in[1];
  const float* bom = (const float*)d_in[2];
  const float* Wze = (const float*)d_in[3];
  const float* bze = (const float*)d_in[4];
  const float* WB  = (const float*)d_in[5];
  const float* bB  = (const float*)d_in[6];
  const float* Cm  = (const float*)d_in[7];
  const float* Dm  = (const float*)d_in[8];
  float* out = (float*)d_out;

  char* ws = (char*)d_ws;
  size_t off = 0;
  bf16raw* u_bf  = (bf16raw*)(ws + off); off += (size_t)16777216*2;    // 32 MB
  bf16raw* Wcat  = (bf16raw*)(ws + off); off += (size_t)262144*2;      // 512 KB
  bf16raw* C_bf  = (bf16raw*)(ws + off); off += (size_t)131072*2;      // 256 KB
  bf16raw* Dm_bf = (bf16raw*)(ws + off); off += (size_t)1048576*2;     // 2 MB
  float*   P     = (float*)  (ws + off);
  bf16raw* Xs    = (bf16raw*)P;          // overlay: P dead after k_coef
  off += (size_t)16384*256*4;                                          // 16 MB
  float4*  Coef  = (float4*) (ws + off); off += (size_t)16384*64*16;   // 16 MB
  float4*  CMw   = (float4*) (ws + off); off += (size_t)128*256*16;    // 512 KB
  float2*  CVw   = (float2*) (ws + off); off += (size_t)128*256*8;     // 256 KB
  float2*  XIn   = (float2*) (ws + off); off += (size_t)128*256*8;     // 256 KB

  k_prep    <<<8896, 256, 0, stream>>>(u, Wom, Wze, WB, Cm, Dm, u_bf, Wcat, C_bf, Dm_bf);
  k_gemm_p  <<<dim3(2, 128), 256, 0, stream>>>(u_bf, Wcat, P);
  k_coef    <<<4096, 256, 0, stream>>>(P, bom, bze, bB, Coef);
  k_scan1   <<<128, 256, 0, stream>>>(Coef, CMw, CVw);
  k_scan2   <<<1, 256, 0, stream>>>(CMw, CVw, XIn);
  k_scan3   <<<128, 256, 0, stream>>>(Coef, XIn, Xs);
  k_gemm_out<<<dim3(4, 128), 256, 0, stream>>>(Xs, u_bf, C_bf, Dm_bf, out);
}